// Round 5
// baseline (4833.820 us; speedup 1.0000x reference)
//
#include <hip/hip_runtime.h>
#include <hip/hip_bf16.h>
#include <stdint.h>

// GraphEncoderTriangleSoup on MI355X (gfx950).  Round 7:
//  - counted-vmcnt ring pipeline (loads stay in flight ACROSS barriers):
//    gemm2: 4 LDS buffers, depth-3, vmcnt(8); gemm1: 3 buffers, depth-2, vmcnt(6)
//    one barrier per K-tile; never drain to 0 in steady state (T3/T4)
//  - global_load_lds width-16 staging, XOR-swizzled 16B groups
//  - BN stats fused in gemm2 epilogue; CSR gathers; XCD swizzle

typedef __hip_bfloat16 bf16;
typedef __attribute__((ext_vector_type(8))) short bf16x8;
typedef __attribute__((ext_vector_type(4))) float f32x4;
#define CHUNK 384

static inline int cdiv(int a, int b) { return (a + b - 1) / b; }

__device__ __forceinline__ float bf2f(bf16 v) { return __bfloat162float(v); }
__device__ __forceinline__ bf16 f2bf(float v) { return __float2bfloat16(v); }
__device__ __forceinline__ unsigned short f2bs(float v) {
  bf16 h = __float2bfloat16(v);
  return *reinterpret_cast<unsigned short*>(&h);
}

// async global->LDS, 16B per lane; LDS dest is wave-uniform base (+lane*16)
__device__ __forceinline__ void gload16(const bf16* g, bf16* lds_base) {
  __builtin_amdgcn_global_load_lds((const __attribute__((address_space(1))) void*)g,
                                   (__attribute__((address_space(3))) void*)lds_base,
                                   16, 0, 0);
}

#define WAIT_VM(N) asm volatile("s_waitcnt vmcnt(" #N ")" ::: "memory")

// Bijective XCD swizzle (m204): contiguous wg ranges per XCD, n fast-varying.
__device__ __forceinline__ void swz_decode(int T, int nn, int& mb, int& nb) {
  int i = blockIdx.x;
  int q = T >> 3, r = T & 7;
  int xcd = i & 7, rank = i >> 3;
  int wg = (xcd < r ? xcd * (q + 1) : r * (q + 1) + (xcd - r) * q) + rank;
  nb = wg % nn;
  mb = wg / nn;
}

// ---------------- embed: x[N,16] -> h[N,224] (bf16, cols 196..223 zero) ----------------
__global__ __launch_bounds__(256) void k_embed(const float* __restrict__ x,
                                               bf16* __restrict__ h, int N) {
  int idx = blockIdx.x * 256 + threadIdx.x;
  if (idx >= N * 224) return;
  int n = idx / 224;
  int c = idx - n * 224;
  float v = 0.f;
  if (c >= 196) {
    v = 0.f;
  } else if (c >= 189) {
    v = x[n * 16 + 9 + (c - 189)];
  } else {
    int g = c / 63;
    int cc = c - g * 63;
    const float* p = x + n * 16 + g * 3;
    if (cc < 3) {
      v = p[cc];
    } else {
      int t = cc - 3;
      int comp = t / 20;
      int rem = t - comp * 20;
      float ang = p[comp] * (float)(1 << (rem >> 1));
      v = (rem & 1) ? cosf(ang) : sinf(ang);
    }
  }
  h[idx] = f2bf(v);
}

// ---------------- degree counting / reciprocals ----------------
__global__ __launch_bounds__(256) void k_count(const int* __restrict__ idxs,
                                               int* __restrict__ deg, int M) {
  int i = blockIdx.x * 256 + threadIdx.x;
  if (i < M) atomicAdd(&deg[idxs[i]], 1);
}

__global__ __launch_bounds__(256) void k_recip(const int* __restrict__ deg,
                                               float* __restrict__ r, int n) {
  int i = blockIdx.x * 256 + threadIdx.x;
  if (i < n) {
    int d = deg[i];
    r[i] = d > 0 ? 1.f / (float)d : 0.f;
  }
}

// ---------------- exclusive scan (single block, 1024 threads) ----------------
__global__ __launch_bounds__(1024) void k_scan(const int* __restrict__ deg,
                                               int* __restrict__ off,
                                               int* __restrict__ cursor, int n) {
  __shared__ int part[1024];
  int t = threadIdx.x;
  int per = (n + 1023) / 1024;
  int b = t * per;
  int e = b + per;
  if (b > n) b = n;
  if (e > n) e = n;
  int s = 0;
  for (int i = b; i < e; ++i) s += deg[i];
  part[t] = s;
  __syncthreads();
  if (t == 0) {
    int r = 0;
    for (int i = 0; i < 1024; ++i) {
      int x = part[i];
      part[i] = r;
      r += x;
    }
    off[n] = r;
  }
  __syncthreads();
  int r = part[t];
  for (int i = b; i < e; ++i) {
    off[i] = r;
    cursor[i] = r;
    r += deg[i];
  }
}

// ---------------- CSR fill ----------------
__global__ __launch_bounds__(256) void k_fill_edges(const int* __restrict__ ei, int E,
                                                    int* __restrict__ cursor,
                                                    int* __restrict__ esrc) {
  int e = blockIdx.x * 256 + threadIdx.x;
  if (e >= E) return;
  int dst = ei[E + e];
  int pos = atomicAdd(&cursor[dst], 1);
  esrc[pos] = ei[e];
}

__global__ __launch_bounds__(256) void k_fill_faces(const int* __restrict__ faces, int M,
                                                    int* __restrict__ cursor,
                                                    int* __restrict__ vidx) {
  int i = blockIdx.x * 256 + threadIdx.x;
  if (i >= M) return;
  int v = faces[i];
  int pos = atomicAdd(&cursor[v], 1);
  vidx[pos] = i;   // i = face_row*3 + slot
}

// ---------------- weight prep: WdT/WbT [H_pad][F_pad] bf16, zero-padded ----------------
__global__ __launch_bounds__(256) void k_prep_w1(const float* __restrict__ w1,
                                                 bf16* __restrict__ WdT,
                                                 bf16* __restrict__ WbT,
                                                 int F, int H, int F_pad, int H_pad) {
  int idx = blockIdx.x * 256 + threadIdx.x;
  if (idx >= H_pad * F_pad) return;
  int n = idx / F_pad;
  int k = idx - n * F_pad;
  float vd = 0.f, vb = 0.f;
  if (n < H && k < F) {
    float top = w1[(size_t)k * H + n];
    float bot = w1[(size_t)(F + k) * H + n];
    vd = top - bot;
    vb = bot;
  }
  WdT[idx] = f2bf(vd);
  WbT[idx] = f2bf(vb);
}

// ---------------- weight prep: W2T [O_pad][H] bf16, zero-padded ----------------
__global__ __launch_bounds__(256) void k_prep_w2(const float* __restrict__ w2,
                                                 bf16* __restrict__ W2T, int H, int O,
                                                 int O_pad) {
  int idx = blockIdx.x * 256 + threadIdx.x;
  if (idx >= O_pad * H) return;
  int n = idx / H;
  int k = idx - n * H;
  float v = (n < O) ? w2[(size_t)k * O + n] : 0.f;
  W2T[idx] = f2bf(v);
}

// ---------------- GEMM1 (MFMA): C = A@Wd + b1, B = A@Wb ----------------
// Counted-vmcnt ring: 3 buffers, depth-2 (stage t+1, wait vmcnt(6) = tile t done).
__global__ __launch_bounds__(256) void gemm1_mfma(
    const bf16* __restrict__ A, int lda,
    const bf16* __restrict__ WdT, const bf16* __restrict__ WbT,
    const float* __restrict__ b1, int c0,
    bf16* __restrict__ outC, bf16* __restrict__ outB,
    int N, int K_pad, int Hc, int nn) {
  __shared__ bf16 sA[3][128 * 32];
  __shared__ bf16 sBd[3][128 * 32];
  __shared__ bf16 sBb[3][128 * 32];
  int mb, nb;
  swz_decode(gridDim.x, nn, mb, nb);
  const int tid = threadIdx.x;
  const int lane = tid & 63, wv = tid >> 6;
  const int wm = wv & 1, wn = wv >> 1;
  const int lr = lane & 15, quad = lane >> 4;
  const int m_blk = mb * 128, n_blk = nb * 128;
  const int rs = lane >> 2;
  const int cg = (lane & 3) ^ ((lane >> 3) & 3);
  const int gsw = (quad ^ ((lr >> 1) & 3)) << 3;
  f32x4 accC[4][4], accB[4][4];
#pragma unroll
  for (int i = 0; i < 4; ++i)
#pragma unroll
    for (int j = 0; j < 4; ++j) {
      accC[i][j] = (f32x4){0.f, 0.f, 0.f, 0.f};
      accB[i][j] = (f32x4){0.f, 0.f, 0.f, 0.f};
    }

  auto stage = [&](int kt, int buf) {
    const int k0 = (kt << 5) + cg * 8;
#pragma unroll
    for (int i = 0; i < 2; ++i) {
      const int rb = wv * 32 + i * 16;
      const int ro = rb + rs;
      gload16(A + (size_t)(m_blk + ro) * lda + k0, &sA[buf][rb * 32]);
      gload16(WdT + (size_t)(n_blk + ro) * K_pad + k0, &sBd[buf][rb * 32]);
      gload16(WbT + (size_t)(n_blk + ro) * K_pad + k0, &sBb[buf][rb * 32]);
    }
  };
  auto compute = [&](int buf) {
    bf16x8 af[4];
#pragma unroll
    for (int im = 0; im < 4; ++im)
      af[im] = *(const bf16x8*)&sA[buf][(wm * 64 + im * 16 + lr) * 32 + gsw];
#pragma unroll
    for (int jn = 0; jn < 4; ++jn) {
      int go = (wn * 64 + jn * 16 + lr) * 32 + gsw;
      bf16x8 bd = *(const bf16x8*)&sBd[buf][go];
      bf16x8 bb = *(const bf16x8*)&sBb[buf][go];
#pragma unroll
      for (int im = 0; im < 4; ++im) {
        accC[im][jn] = __builtin_amdgcn_mfma_f32_16x16x32_bf16(af[im], bd, accC[im][jn], 0, 0, 0);
        accB[im][jn] = __builtin_amdgcn_mfma_f32_16x16x32_bf16(af[im], bb, accB[im][jn], 0, 0, 0);
      }
    }
  };

  const int kTiles = K_pad >> 5;
  stage(0, 0);
  int bt;
  for (int kt = 0; kt < kTiles; ++kt) {
    if (kt + 1 < kTiles) {
      bt = kt + 1;
      stage(bt, bt - (bt / 3) * 3);
      WAIT_VM(6);           // tile kt landed; tile kt+1 stays in flight
    } else {
      WAIT_VM(0);
    }
    __builtin_amdgcn_s_barrier();
    compute(kt - (kt / 3) * 3);
  }

#pragma unroll
  for (int jn = 0; jn < 4; ++jn) {
    int c = n_blk + wn * 64 + jn * 16 + lr;
    if (c >= Hc) continue;
    float bv = b1[c0 + c];
#pragma unroll
    for (int im = 0; im < 4; ++im) {
      int mb2 = m_blk + wm * 64 + im * 16 + quad * 4;
#pragma unroll
      for (int rg = 0; rg < 4; ++rg) {
        int r = mb2 + rg;
        if (r >= N) continue;
        size_t o = (size_t)r * Hc + c;
        outC[o] = f2bf(accC[im][jn][rg] + bv);
        outB[o] = f2bf(accB[im][jn][rg]);
      }
    }
  }
}

// ---------------- GEMM2 (MFMA): Eo = (S@W2)*rdeg (+b2 if deg>0), fused BN stats ----------------
// Counted-vmcnt ring: 4 buffers, depth-3 (stage t+2, wait vmcnt(8) = tile t done).
__global__ __launch_bounds__(256) void gemm2_mfma(
    const bf16* __restrict__ S, int ldS,
    const bf16* __restrict__ W2T, int ldw,
    const float* __restrict__ b2, const float* __restrict__ rdeg,
    float* __restrict__ Eo, float* __restrict__ stats, int do_stats,
    int N, int K, int O, int nn) {
  __shared__ bf16 sA[4][128 * 32];
  __shared__ bf16 sB[4][128 * 32];
  int mb, nb;
  swz_decode(gridDim.x, nn, mb, nb);
  const int tid = threadIdx.x;
  const int lane = tid & 63, wv = tid >> 6;
  const int wm = wv & 1, wn = wv >> 1;
  const int lr = lane & 15, quad = lane >> 4;
  const int m_blk = mb * 128, n_blk = nb * 128;
  const int rs = lane >> 2;
  const int cg = (lane & 3) ^ ((lane >> 3) & 3);
  const int gsw = (quad ^ ((lr >> 1) & 3)) << 3;
  f32x4 acc[4][4];
#pragma unroll
  for (int i = 0; i < 4; ++i)
#pragma unroll
    for (int j = 0; j < 4; ++j) acc[i][j] = (f32x4){0.f, 0.f, 0.f, 0.f};

  auto stage = [&](int kt, int buf) {
    const int k0 = (kt << 5) + cg * 8;
#pragma unroll
    for (int i = 0; i < 2; ++i) {
      const int rb = wv * 32 + i * 16;
      const int ro = rb + rs;
      gload16(S + (size_t)(m_blk + ro) * ldS + k0, &sA[buf][rb * 32]);
      gload16(W2T + (size_t)(n_blk + ro) * ldw + k0, &sB[buf][rb * 32]);
    }
  };
  auto compute = [&](int buf) {
    bf16x8 af[4];
#pragma unroll
    for (int im = 0; im < 4; ++im)
      af[im] = *(const bf16x8*)&sA[buf][(wm * 64 + im * 16 + lr) * 32 + gsw];
#pragma unroll
    for (int jn = 0; jn < 4; ++jn) {
      bf16x8 bb = *(const bf16x8*)&sB[buf][(wn * 64 + jn * 16 + lr) * 32 + gsw];
#pragma unroll
      for (int im = 0; im < 4; ++im)
        acc[im][jn] = __builtin_amdgcn_mfma_f32_16x16x32_bf16(af[im], bb, acc[im][jn], 0, 0, 0);
    }
  };

  const int kTiles = K >> 5;
  stage(0, 0);
  stage(1, 1);
  for (int kt = 0; kt < kTiles; ++kt) {
    if (kt + 2 < kTiles) {
      stage(kt + 2, (kt + 2) & 3);
      WAIT_VM(8);           // tile kt landed; kt+1, kt+2 stay in flight
    } else if (kt + 1 < kTiles) {
      WAIT_VM(4);           // tile kt landed; kt+1 in flight
    } else {
      WAIT_VM(0);
    }
    __builtin_amdgcn_s_barrier();
    compute(kt & 3);
  }

  // hoisted per-row reciprocal degrees
  float rdv[4][4];
#pragma unroll
  for (int im = 0; im < 4; ++im) {
    int mb2 = m_blk + wm * 64 + im * 16 + quad * 4;
#pragma unroll
    for (int rg = 0; rg < 4; ++rg) {
      int r = mb2 + rg;
      rdv[im][rg] = (r < N) ? rdeg[r] : 0.f;
    }
  }
#pragma unroll
  for (int jn = 0; jn < 4; ++jn) {
    int c = n_blk + wn * 64 + jn * 16 + lr;
    if (c >= O) continue;
    float b2v = b2[c];
    float ssum = 0.f, qsum = 0.f;
#pragma unroll
    for (int im = 0; im < 4; ++im) {
      int mb2 = m_blk + wm * 64 + im * 16 + quad * 4;
#pragma unroll
      for (int rg = 0; rg < 4; ++rg) {
        int r = mb2 + rg;
        if (r >= N) continue;
        float rd = rdv[im][rg];
        float v = acc[im][jn][rg] * rd;
        if (rd != 0.f) v += b2v;
        Eo[(size_t)r * O + c] = v;
        ssum += v;
        qsum += v * v;
      }
    }
    if (do_stats) {
      ssum += __shfl_xor(ssum, 16);
      ssum += __shfl_xor(ssum, 32);
      qsum += __shfl_xor(qsum, 16);
      qsum += __shfl_xor(qsum, 32);
      if (quad == 0) {
        unsafeAtomicAdd(&stats[c], ssum);
        unsafeAtomicAdd(&stats[O + c], qsum);
      }
    }
  }
}

// ---------------- edge gather: S[n, c0:c0+Hc] = sum relu(C[n] + B[src]), bf16 out ----------------
__global__ __launch_bounds__(256) void k_edge_gather(
    const int* __restrict__ eoff, const int* __restrict__ esrc,
    const bf16* __restrict__ C, const bf16* __restrict__ B,
    bf16* __restrict__ S, int ldS, int c0, int N, int Hc) {
  int gw = (blockIdx.x * 256 + threadIdx.x) >> 6;
  int lane = threadIdx.x & 63;
  if (gw >= N) return;
  int beg = eoff[gw], end = eoff[gw + 1];
  const uint32_t* Crow = reinterpret_cast<const uint32_t*>(C + (size_t)gw * Hc);
  float cc0[3], cc1[3], acc0[3], acc1[3];
#pragma unroll
  for (int w = 0; w < 3; ++w) {
    acc0[w] = 0.f;
    acc1[w] = 0.f;
    cc0[w] = 0.f;
    cc1[w] = 0.f;
    int j2 = lane + w * 64;
    if (j2 * 2 < Hc) {
      uint32_t uc = Crow[j2];
      cc0[w] = __uint_as_float(uc << 16);
      cc1[w] = __uint_as_float(uc & 0xffff0000u);
    }
  }
  for (int e = beg; e < end; ++e) {
    int src = esrc[e];
    const uint32_t* Brow = reinterpret_cast<const uint32_t*>(B + (size_t)src * Hc);
#pragma unroll
    for (int w = 0; w < 3; ++w) {
      int j2 = lane + w * 64;
      if (j2 * 2 < Hc) {
        uint32_t ub = Brow[j2];
        acc0[w] += fmaxf(cc0[w] + __uint_as_float(ub << 16), 0.f);
        acc1[w] += fmaxf(cc1[w] + __uint_as_float(ub & 0xffff0000u), 0.f);
      }
    }
  }
  uint32_t* Srow = reinterpret_cast<uint32_t*>(S + (size_t)gw * ldS + c0);
#pragma unroll
  for (int w = 0; w < 3; ++w) {
    int j2 = lane + w * 64;
    if (j2 * 2 < Hc)
      Srow[j2] = ((uint32_t)f2bs(acc1[w]) << 16) | (uint32_t)f2bs(acc0[w]);
  }
}

// ---------------- BN finalize ----------------
__global__ __launch_bounds__(256) void k_bn_finalize(const float* __restrict__ stats,
                                                     const float* __restrict__ gamma,
                                                     const float* __restrict__ beta,
                                                     float* __restrict__ scale,
                                                     float* __restrict__ shift, int N, int O) {
  int c = blockIdx.x * 256 + threadIdx.x;
  if (c >= O) return;
  float mu = stats[c] / (float)N;
  float var = stats[O + c] / (float)N - mu * mu;
  float sc = gamma[c] * rsqrtf(var + 1e-5f);
  scale[c] = sc;
  shift[c] = beta[c] - mu * sc;
}

// ---------------- vertex gather: Vf[v][c] = sum_{(n,g) in CSR(v)} bnrelu(Ef[n][g*O3+c]) ----------------
__global__ __launch_bounds__(256) void k_vgather(
    const int* __restrict__ voff, const int* __restrict__ vidx,
    const float* __restrict__ Ef, const float* __restrict__ scale,
    const float* __restrict__ shift, int use_bn,
    float* __restrict__ Vf, int V, int O, int O3) {
  int idx = blockIdx.x * 256 + threadIdx.x;
  if (idx >= V * O3) return;
  int v = idx / O3;
  int c = idx - v * O3;
  int beg = voff[v], end = voff[v + 1];
  float acc = 0.f;
  for (int e = beg; e < end; ++e) {
    int i = vidx[e];            // face_row*3 + slot
    int n = i / 3;
    int g = i - n * 3;
    int col = g * O3 + c;
    float x = Ef[(size_t)n * O + col];
    if (use_bn) x = fmaxf(fmaf(x, scale[col], shift[col]), 0.f);
    acc += x;
  }
  Vf[idx] = acc;
}

// ---------------- vertex mean gather back ----------------
__global__ __launch_bounds__(256) void k_gather_bf16(const float* __restrict__ Vf,
                                                     const int* __restrict__ faces,
                                                     const float* __restrict__ rv,
                                                     bf16* __restrict__ out,
                                                     int N, int O, int O3) {
  int idx = blockIdx.x * 256 + threadIdx.x;
  if (idx >= N * O) return;
  int n = idx / O;
  int c = idx - n * O;
  int g = c / O3;
  int vert = faces[n * 3 + g];
  out[idx] = f2bf(Vf[(size_t)vert * O3 + (c - g * O3)] * rv[vert]);
}

__global__ __launch_bounds__(256) void k_gather_f32(const float* __restrict__ Vf,
                                                    const int* __restrict__ faces,
                                                    const float* __restrict__ rv,
                                                    float* __restrict__ out,
                                                    int N, int O, int O3) {
  int idx = blockIdx.x * 256 + threadIdx.x;
  if (idx >= N * O) return;
  int n = idx / O;
  int c = idx - n * O;
  int g = c / O3;
  int vert = faces[n * 3 + g];
  out[idx] = Vf[(size_t)vert * O3 + (c - g * O3)] * rv[vert];
}

extern "C" void kernel_launch(void* const* d_in, const int* in_sizes, int n_in,
                              void* d_out, int out_size, void* d_ws, size_t ws_size,
                              hipStream_t stream) {
  (void)n_in; (void)out_size; (void)ws_size;
  const float* x = (const float*)d_in[0];
  const int* ei = (const int*)d_in[1];
  const int* faces = (const int*)d_in[2];
  const int N = in_sizes[0] / 16;
  const int E = in_sizes[1] / 2;
  const int V = 50000;
  const int N_pad = cdiv(N, 128) * 128;   // staging reads go to N_pad-1; stores guarded

  char* p = (char*)d_ws;
  auto carve = [&](size_t bytes) -> char* {
    char* r = p;
    p += (bytes + 255) & ~(size_t)255;
    return r;
  };
  bf16* buf_h = (bf16*)carve((size_t)N_pad * 384 * sizeof(bf16));
  float* buf_e = (float*)carve((size_t)N * 384 * sizeof(float));
  bf16* buf_C = (bf16*)carve((size_t)N * CHUNK * sizeof(bf16));
  bf16* buf_B = (bf16*)carve((size_t)N * CHUNK * sizeof(bf16));
  bf16* buf_S = (bf16*)carve((size_t)N_pad * 1152 * sizeof(bf16));
  float* buf_V = (float*)carve((size_t)V * 192 * sizeof(float));
  bf16* buf_WdT = (bf16*)carve((size_t)1050000 * sizeof(bf16));
  bf16* buf_WbT = (bf16*)carve((size_t)1050000 * sizeof(bf16));
  bf16* buf_W2T = (bf16*)carve((size_t)1500000 * sizeof(bf16));
  int* ideg = (int*)carve((size_t)N * 4);
  int* ivdeg = (int*)carve((size_t)V * 4);
  float* rdegN = (float*)carve((size_t)N * 4);
  float* rdegV = (float*)carve((size_t)V * 4);
  float* stats = (float*)carve(2 * 576 * 4);
  float* scale = (float*)carve(576 * 4);
  float* shift = (float*)carve(576 * 4);
  int* e_off = (int*)carve((size_t)(N + 1) * 4);
  int* e_cur = (int*)carve((size_t)N * 4);
  int* e_src = (int*)carve((size_t)E * 4);
  int* v_off = (int*)carve((size_t)(V + 1) * 4);
  int* v_cur = (int*)carve((size_t)V * 4);
  int* v_idx = (int*)carve((size_t)3 * N * 4);

  hipMemsetAsync(ideg, 0, (size_t)N * 4, stream);
  hipMemsetAsync(ivdeg, 0, (size_t)V * 4, stream);
  k_count<<<cdiv(E, 256), 256, 0, stream>>>(ei + E, ideg, E);
  k_count<<<cdiv(3 * N, 256), 256, 0, stream>>>(faces, ivdeg, 3 * N);
  k_recip<<<cdiv(N, 256), 256, 0, stream>>>(ideg, rdegN, N);
  k_recip<<<cdiv(V, 256), 256, 0, stream>>>(ivdeg, rdegV, V);

  k_scan<<<1, 1024, 0, stream>>>(ideg, e_off, e_cur, N);
  k_scan<<<1, 1024, 0, stream>>>(ivdeg, v_off, v_cur, V);
  k_fill_edges<<<cdiv(E, 256), 256, 0, stream>>>(ei, E, e_cur, e_src);
  k_fill_faces<<<cdiv(3 * N, 256), 256, 0, stream>>>(faces, 3 * N, v_cur, v_idx);

  k_embed<<<cdiv(N * 224, 256), 256, 0, stream>>>(x, buf_h, N);

  const int LF[5] = {196, 96, 192, 384, 384};
  const int LH[5] = {192, 384, 768, 768, 1152};
  const int LO[5] = {96, 192, 384, 384, 576};

  size_t off1 = 0, off2 = 0;
  const int nm = cdiv(N, 128);

  for (int l = 0; l < 5; ++l) {
    const int F = LF[l], H = LH[l], O = LO[l], O3 = O / 3;
    const int F_pad = ((F + 31) / 32) * 32;
    int Hc_last = H % CHUNK;
    if (Hc_last == 0) Hc_last = CHUNK;
    const int H_pad = H - Hc_last + cdiv(Hc_last, 128) * 128;
    const int O_pad = cdiv(O, 128) * 128;
    const float* w1 = (const float*)d_in[4 + l * 4];
    const float* b1 = (const float*)d_in[5 + l * 4];
    const float* w2 = (const float*)d_in[6 + l * 4];
    const float* b2 = (const float*)d_in[7 + l * 4];
    float* Ebuf = (l == 4) ? (float*)d_out : buf_e;
    bf16* WdT = buf_WdT + off1;
    bf16* WbT = buf_WbT + off1;
    bf16* W2T = buf_W2T + off2;
    off1 += (size_t)H_pad * F_pad;
    off2 += (size_t)O_pad * H;

    k_prep_w1<<<cdiv(H_pad * F_pad, 256), 256, 0, stream>>>(w1, WdT, WbT, F, H, F_pad, H_pad);
    k_prep_w2<<<cdiv(O_pad * H, 256), 256, 0, stream>>>(w2, W2T, H, O, O_pad);

    for (int c0 = 0; c0 < H; c0 += CHUNK) {
      int Hc = (H - c0 < CHUNK) ? (H - c0) : CHUNK;
      int nn1 = cdiv(Hc, 128);
      gemm1_mfma<<<nm * nn1, 256, 0, stream>>>(buf_h, F_pad,
                                               WdT + (size_t)c0 * F_pad, WbT + (size_t)c0 * F_pad,
                                               b1, c0, buf_C, buf_B, N, F_pad, Hc, nn1);
      k_edge_gather<<<cdiv(N * 64, 256), 256, 0, stream>>>(e_off, e_src, buf_C, buf_B,
                                                           buf_S, H, c0, N, Hc);
    }

    if (l < 4) hipMemsetAsync(stats, 0, (size_t)2 * O * 4, stream);
    int nn2 = cdiv(O, 128);
    gemm2_mfma<<<nm * nn2, 256, 0, stream>>>(buf_S, H, W2T, H, b2, rdegN, Ebuf,
                                             stats, (l < 4) ? 1 : 0, N, H, O, nn2);

    if (l < 4)
      k_bn_finalize<<<cdiv(O, 256), 256, 0, stream>>>(
          stats, (const float*)d_in[24 + l * 2], (const float*)d_in[25 + l * 2],
          scale, shift, N, O);

    k_vgather<<<cdiv(V * O3, 256), 256, 0, stream>>>(v_off, v_idx, Ebuf, scale, shift,
                                                     (l < 4) ? 1 : 0, buf_V, V, O, O3);
    if (l < 4)
      k_gather_bf16<<<cdiv(N * O, 256), 256, 0, stream>>>(buf_V, faces, rdegV, buf_h, N, O, O3);
    else
      k_gather_f32<<<cdiv(N * O, 256), 256, 0, stream>>>(buf_V, faces, rdegV, (float*)d_out, N, O, O3);
  }
}

// Round 6
// 4282.034 us; speedup vs baseline: 1.1289x; 1.1289x over previous
//
#include <hip/hip_runtime.h>
#include <hip/hip_bf16.h>
#include <stdint.h>

// GraphEncoderTriangleSoup on MI355X (gfx950).  Round 8:
//  - GEMMs: R4's 2-phase double-buffer (32/48 KB LDS) — R5's deep ring reverted
//    (64 KB LDS capped occupancy at 2 blocks/CU, net loss)
//  - edge_gather: 3-edge batched loads (one LLC-latency stall per node, 9 row
//    loads in flight) instead of per-edge serialized chain
//  - global_load_lds width-16 staging, XOR-swizzled 16B groups
//  - BN stats fused in gemm2 epilogue; CSR gathers; XCD swizzle

typedef __hip_bfloat16 bf16;
typedef __attribute__((ext_vector_type(8))) short bf16x8;
typedef __attribute__((ext_vector_type(4))) float f32x4;
#define CHUNK 384

static inline int cdiv(int a, int b) { return (a + b - 1) / b; }

__device__ __forceinline__ float bf2f(bf16 v) { return __bfloat162float(v); }
__device__ __forceinline__ bf16 f2bf(float v) { return __float2bfloat16(v); }
__device__ __forceinline__ unsigned short f2bs(float v) {
  bf16 h = __float2bfloat16(v);
  return *reinterpret_cast<unsigned short*>(&h);
}

// async global->LDS, 16B per lane; LDS dest is wave-uniform base (+lane*16)
__device__ __forceinline__ void gload16(const bf16* g, bf16* lds_base) {
  __builtin_amdgcn_global_load_lds((const __attribute__((address_space(1))) void*)g,
                                   (__attribute__((address_space(3))) void*)lds_base,
                                   16, 0, 0);
}

#define WAIT_VM0 asm volatile("s_waitcnt vmcnt(0)" ::: "memory")

// Bijective XCD swizzle (m204): contiguous wg ranges per XCD, n fast-varying.
__device__ __forceinline__ void swz_decode(int T, int nn, int& mb, int& nb) {
  int i = blockIdx.x;
  int q = T >> 3, r = T & 7;
  int xcd = i & 7, rank = i >> 3;
  int wg = (xcd < r ? xcd * (q + 1) : r * (q + 1) + (xcd - r) * q) + rank;
  nb = wg % nn;
  mb = wg / nn;
}

// ---------------- embed: x[N,16] -> h[N,224] (bf16, cols 196..223 zero) ----------------
__global__ __launch_bounds__(256) void k_embed(const float* __restrict__ x,
                                               bf16* __restrict__ h, int N) {
  int idx = blockIdx.x * 256 + threadIdx.x;
  if (idx >= N * 224) return;
  int n = idx / 224;
  int c = idx - n * 224;
  float v = 0.f;
  if (c >= 196) {
    v = 0.f;
  } else if (c >= 189) {
    v = x[n * 16 + 9 + (c - 189)];
  } else {
    int g = c / 63;
    int cc = c - g * 63;
    const float* p = x + n * 16 + g * 3;
    if (cc < 3) {
      v = p[cc];
    } else {
      int t = cc - 3;
      int comp = t / 20;
      int rem = t - comp * 20;
      float ang = p[comp] * (float)(1 << (rem >> 1));
      v = (rem & 1) ? cosf(ang) : sinf(ang);
    }
  }
  h[idx] = f2bf(v);
}

// ---------------- degree counting / reciprocals ----------------
__global__ __launch_bounds__(256) void k_count(const int* __restrict__ idxs,
                                               int* __restrict__ deg, int M) {
  int i = blockIdx.x * 256 + threadIdx.x;
  if (i < M) atomicAdd(&deg[idxs[i]], 1);
}

__global__ __launch_bounds__(256) void k_recip(const int* __restrict__ deg,
                                               float* __restrict__ r, int n) {
  int i = blockIdx.x * 256 + threadIdx.x;
  if (i < n) {
    int d = deg[i];
    r[i] = d > 0 ? 1.f / (float)d : 0.f;
  }
}

// ---------------- exclusive scan (single block, 1024 threads) ----------------
__global__ __launch_bounds__(1024) void k_scan(const int* __restrict__ deg,
                                               int* __restrict__ off,
                                               int* __restrict__ cursor, int n) {
  __shared__ int part[1024];
  int t = threadIdx.x;
  int per = (n + 1023) / 1024;
  int b = t * per;
  int e = b + per;
  if (b > n) b = n;
  if (e > n) e = n;
  int s = 0;
  for (int i = b; i < e; ++i) s += deg[i];
  part[t] = s;
  __syncthreads();
  if (t == 0) {
    int r = 0;
    for (int i = 0; i < 1024; ++i) {
      int x = part[i];
      part[i] = r;
      r += x;
    }
    off[n] = r;
  }
  __syncthreads();
  int r = part[t];
  for (int i = b; i < e; ++i) {
    off[i] = r;
    cursor[i] = r;
    r += deg[i];
  }
}

// ---------------- CSR fill ----------------
__global__ __launch_bounds__(256) void k_fill_edges(const int* __restrict__ ei, int E,
                                                    int* __restrict__ cursor,
                                                    int* __restrict__ esrc) {
  int e = blockIdx.x * 256 + threadIdx.x;
  if (e >= E) return;
  int dst = ei[E + e];
  int pos = atomicAdd(&cursor[dst], 1);
  esrc[pos] = ei[e];
}

__global__ __launch_bounds__(256) void k_fill_faces(const int* __restrict__ faces, int M,
                                                    int* __restrict__ cursor,
                                                    int* __restrict__ vidx) {
  int i = blockIdx.x * 256 + threadIdx.x;
  if (i >= M) return;
  int v = faces[i];
  int pos = atomicAdd(&cursor[v], 1);
  vidx[pos] = i;   // i = face_row*3 + slot
}

// ---------------- weight prep: WdT/WbT [H_pad][F_pad] bf16, zero-padded ----------------
__global__ __launch_bounds__(256) void k_prep_w1(const float* __restrict__ w1,
                                                 bf16* __restrict__ WdT,
                                                 bf16* __restrict__ WbT,
                                                 int F, int H, int F_pad, int H_pad) {
  int idx = blockIdx.x * 256 + threadIdx.x;
  if (idx >= H_pad * F_pad) return;
  int n = idx / F_pad;
  int k = idx - n * F_pad;
  float vd = 0.f, vb = 0.f;
  if (n < H && k < F) {
    float top = w1[(size_t)k * H + n];
    float bot = w1[(size_t)(F + k) * H + n];
    vd = top - bot;
    vb = bot;
  }
  WdT[idx] = f2bf(vd);
  WbT[idx] = f2bf(vb);
}

// ---------------- weight prep: W2T [O_pad][H] bf16, zero-padded ----------------
__global__ __launch_bounds__(256) void k_prep_w2(const float* __restrict__ w2,
                                                 bf16* __restrict__ W2T, int H, int O,
                                                 int O_pad) {
  int idx = blockIdx.x * 256 + threadIdx.x;
  if (idx >= O_pad * H) return;
  int n = idx / H;
  int k = idx - n * H;
  float v = (n < O) ? w2[(size_t)k * O + n] : 0.f;
  W2T[idx] = f2bf(v);
}

// ---------------- GEMM1 (MFMA): C = A@Wd + b1, B = A@Wb ----------------
// 2-phase dbuf pipeline; gload_lds staging; XOR-swizzled 16B groups.
__global__ __launch_bounds__(256) void gemm1_mfma(
    const bf16* __restrict__ A, int lda,
    const bf16* __restrict__ WdT, const bf16* __restrict__ WbT,
    const float* __restrict__ b1, int c0,
    bf16* __restrict__ outC, bf16* __restrict__ outB,
    int N, int K_pad, int Hc, int nn) {
  __shared__ bf16 sA[2][128 * 32];
  __shared__ bf16 sBd[2][128 * 32];
  __shared__ bf16 sBb[2][128 * 32];
  int mb, nb;
  swz_decode(gridDim.x, nn, mb, nb);
  const int tid = threadIdx.x;
  const int lane = tid & 63, wv = tid >> 6;
  const int wm = wv & 1, wn = wv >> 1;
  const int lr = lane & 15, quad = lane >> 4;
  const int m_blk = mb * 128, n_blk = nb * 128;
  const int rs = lane >> 2;
  const int cg = (lane & 3) ^ ((lane >> 3) & 3);
  const int gsw = (quad ^ ((lr >> 1) & 3)) << 3;
  f32x4 accC[4][4], accB[4][4];
#pragma unroll
  for (int i = 0; i < 4; ++i)
#pragma unroll
    for (int j = 0; j < 4; ++j) {
      accC[i][j] = (f32x4){0.f, 0.f, 0.f, 0.f};
      accB[i][j] = (f32x4){0.f, 0.f, 0.f, 0.f};
    }

  auto stage = [&](int kt, int buf) {
    const int k0 = (kt << 5) + cg * 8;
#pragma unroll
    for (int i = 0; i < 2; ++i) {
      const int rb = wv * 32 + i * 16;
      const int ro = rb + rs;
      gload16(A + (size_t)(m_blk + ro) * lda + k0, &sA[buf][rb * 32]);
      gload16(WdT + (size_t)(n_blk + ro) * K_pad + k0, &sBd[buf][rb * 32]);
      gload16(WbT + (size_t)(n_blk + ro) * K_pad + k0, &sBb[buf][rb * 32]);
    }
  };
  auto compute = [&](int buf) {
    bf16x8 af[4];
#pragma unroll
    for (int im = 0; im < 4; ++im)
      af[im] = *(const bf16x8*)&sA[buf][(wm * 64 + im * 16 + lr) * 32 + gsw];
#pragma unroll
    for (int jn = 0; jn < 4; ++jn) {
      int go = (wn * 64 + jn * 16 + lr) * 32 + gsw;
      bf16x8 bd = *(const bf16x8*)&sBd[buf][go];
      bf16x8 bb = *(const bf16x8*)&sBb[buf][go];
#pragma unroll
      for (int im = 0; im < 4; ++im) {
        accC[im][jn] = __builtin_amdgcn_mfma_f32_16x16x32_bf16(af[im], bd, accC[im][jn], 0, 0, 0);
        accB[im][jn] = __builtin_amdgcn_mfma_f32_16x16x32_bf16(af[im], bb, accB[im][jn], 0, 0, 0);
      }
    }
  };

  const int kTiles = K_pad >> 5;
  stage(0, 0);
  WAIT_VM0;
  __builtin_amdgcn_s_barrier();
  int cur = 0;
  for (int kt = 0; kt < kTiles - 1; ++kt) {
    stage(kt + 1, cur ^ 1);
    compute(cur);
    WAIT_VM0;
    __builtin_amdgcn_s_barrier();
    cur ^= 1;
  }
  compute(cur);

#pragma unroll
  for (int jn = 0; jn < 4; ++jn) {
    int c = n_blk + wn * 64 + jn * 16 + lr;
    if (c >= Hc) continue;
    float bv = b1[c0 + c];
#pragma unroll
    for (int im = 0; im < 4; ++im) {
      int mb2 = m_blk + wm * 64 + im * 16 + quad * 4;
#pragma unroll
      for (int rg = 0; rg < 4; ++rg) {
        int r = mb2 + rg;
        if (r >= N) continue;
        size_t o = (size_t)r * Hc + c;
        outC[o] = f2bf(accC[im][jn][rg] + bv);
        outB[o] = f2bf(accB[im][jn][rg]);
      }
    }
  }
}

// ---------------- GEMM2 (MFMA): Eo = (S@W2)*rdeg (+b2 if deg>0), fused BN stats ----------------
__global__ __launch_bounds__(256) void gemm2_mfma(
    const bf16* __restrict__ S, int ldS,
    const bf16* __restrict__ W2T, int ldw,
    const float* __restrict__ b2, const float* __restrict__ rdeg,
    float* __restrict__ Eo, float* __restrict__ stats, int do_stats,
    int N, int K, int O, int nn) {
  __shared__ bf16 sA[2][128 * 32];
  __shared__ bf16 sB[2][128 * 32];
  int mb, nb;
  swz_decode(gridDim.x, nn, mb, nb);
  const int tid = threadIdx.x;
  const int lane = tid & 63, wv = tid >> 6;
  const int wm = wv & 1, wn = wv >> 1;
  const int lr = lane & 15, quad = lane >> 4;
  const int m_blk = mb * 128, n_blk = nb * 128;
  const int rs = lane >> 2;
  const int cg = (lane & 3) ^ ((lane >> 3) & 3);
  const int gsw = (quad ^ ((lr >> 1) & 3)) << 3;
  f32x4 acc[4][4];
#pragma unroll
  for (int i = 0; i < 4; ++i)
#pragma unroll
    for (int j = 0; j < 4; ++j) acc[i][j] = (f32x4){0.f, 0.f, 0.f, 0.f};

  auto stage = [&](int kt, int buf) {
    const int k0 = (kt << 5) + cg * 8;
#pragma unroll
    for (int i = 0; i < 2; ++i) {
      const int rb = wv * 32 + i * 16;
      const int ro = rb + rs;
      gload16(S + (size_t)(m_blk + ro) * ldS + k0, &sA[buf][rb * 32]);
      gload16(W2T + (size_t)(n_blk + ro) * ldw + k0, &sB[buf][rb * 32]);
    }
  };
  auto compute = [&](int buf) {
    bf16x8 af[4];
#pragma unroll
    for (int im = 0; im < 4; ++im)
      af[im] = *(const bf16x8*)&sA[buf][(wm * 64 + im * 16 + lr) * 32 + gsw];
#pragma unroll
    for (int jn = 0; jn < 4; ++jn) {
      bf16x8 bb = *(const bf16x8*)&sB[buf][(wn * 64 + jn * 16 + lr) * 32 + gsw];
#pragma unroll
      for (int im = 0; im < 4; ++im)
        acc[im][jn] = __builtin_amdgcn_mfma_f32_16x16x32_bf16(af[im], bb, acc[im][jn], 0, 0, 0);
    }
  };

  const int kTiles = K >> 5;
  stage(0, 0);
  WAIT_VM0;
  __builtin_amdgcn_s_barrier();
  int cur = 0;
  for (int kt = 0; kt < kTiles - 1; ++kt) {
    stage(kt + 1, cur ^ 1);
    compute(cur);
    WAIT_VM0;
    __builtin_amdgcn_s_barrier();
    cur ^= 1;
  }
  compute(cur);

  // hoisted per-row reciprocal degrees
  float rdv[4][4];
#pragma unroll
  for (int im = 0; im < 4; ++im) {
    int mb2 = m_blk + wm * 64 + im * 16 + quad * 4;
#pragma unroll
    for (int rg = 0; rg < 4; ++rg) {
      int r = mb2 + rg;
      rdv[im][rg] = (r < N) ? rdeg[r] : 0.f;
    }
  }
#pragma unroll
  for (int jn = 0; jn < 4; ++jn) {
    int c = n_blk + wn * 64 + jn * 16 + lr;
    if (c >= O) continue;
    float b2v = b2[c];
    float ssum = 0.f, qsum = 0.f;
#pragma unroll
    for (int im = 0; im < 4; ++im) {
      int mb2 = m_blk + wm * 64 + im * 16 + quad * 4;
#pragma unroll
      for (int rg = 0; rg < 4; ++rg) {
        int r = mb2 + rg;
        if (r >= N) continue;
        float rd = rdv[im][rg];
        float v = acc[im][jn][rg] * rd;
        if (rd != 0.f) v += b2v;
        Eo[(size_t)r * O + c] = v;
        ssum += v;
        qsum += v * v;
      }
    }
    if (do_stats) {
      ssum += __shfl_xor(ssum, 16);
      ssum += __shfl_xor(ssum, 32);
      qsum += __shfl_xor(qsum, 16);
      qsum += __shfl_xor(qsum, 32);
      if (quad == 0) {
        unsafeAtomicAdd(&stats[c], ssum);
        unsafeAtomicAdd(&stats[O + c], qsum);
      }
    }
  }
}

// ---------------- edge gather: S[n, c0:c0+Hc] = sum relu(C[n] + B[src]), bf16 out ----------------
// Batched: up to 3 edges per iteration -> 9 row loads issued back-to-back,
// one latency stall per batch instead of per edge.
__global__ __launch_bounds__(256) void k_edge_gather(
    const int* __restrict__ eoff, const int* __restrict__ esrc,
    const bf16* __restrict__ C, const bf16* __restrict__ B,
    bf16* __restrict__ S, int ldS, int c0, int N, int Hc) {
  int gw = (blockIdx.x * 256 + threadIdx.x) >> 6;
  int lane = threadIdx.x & 63;
  if (gw >= N) return;
  int beg = eoff[gw], end = eoff[gw + 1];
  const int nw = Hc >> 1;   // uint32 words per row
  int j2w[3];
  float cc0[3], cc1[3], a0[3], a1[3];
  const uint32_t* Crow = reinterpret_cast<const uint32_t*>(C + (size_t)gw * Hc);
#pragma unroll
  for (int w = 0; w < 3; ++w) {
    j2w[w] = lane + w * 64;
    a0[w] = a1[w] = 0.f;
    cc0[w] = cc1[w] = 0.f;
    if (j2w[w] < nw) {
      uint32_t uc = Crow[j2w[w]];
      cc0[w] = __uint_as_float(uc << 16);
      cc1[w] = __uint_as_float(uc & 0xffff0000u);
    }
  }
  int e = beg;
  while (e < end) {
    int m = end - e;
    int take = (m < 3) ? m : 3;
    const uint32_t* R0 = reinterpret_cast<const uint32_t*>(B + (size_t)esrc[e] * Hc);
    const uint32_t* R1 =
        (take > 1) ? reinterpret_cast<const uint32_t*>(B + (size_t)esrc[e + 1] * Hc) : R0;
    const uint32_t* R2 =
        (take > 2) ? reinterpret_cast<const uint32_t*>(B + (size_t)esrc[e + 2] * Hc) : R0;
    uint32_t rA[3] = {0u, 0u, 0u}, rB_[3] = {0u, 0u, 0u}, rC_[3] = {0u, 0u, 0u};
#pragma unroll
    for (int w = 0; w < 3; ++w)
      if (j2w[w] < nw) rA[w] = R0[j2w[w]];
    if (take > 1) {
#pragma unroll
      for (int w = 0; w < 3; ++w)
        if (j2w[w] < nw) rB_[w] = R1[j2w[w]];
    }
    if (take > 2) {
#pragma unroll
      for (int w = 0; w < 3; ++w)
        if (j2w[w] < nw) rC_[w] = R2[j2w[w]];
    }
#pragma unroll
    for (int w = 0; w < 3; ++w) {
      a0[w] += fmaxf(cc0[w] + __uint_as_float(rA[w] << 16), 0.f);
      a1[w] += fmaxf(cc1[w] + __uint_as_float(rA[w] & 0xffff0000u), 0.f);
    }
    if (take > 1) {
#pragma unroll
      for (int w = 0; w < 3; ++w) {
        a0[w] += fmaxf(cc0[w] + __uint_as_float(rB_[w] << 16), 0.f);
        a1[w] += fmaxf(cc1[w] + __uint_as_float(rB_[w] & 0xffff0000u), 0.f);
      }
    }
    if (take > 2) {
#pragma unroll
      for (int w = 0; w < 3; ++w) {
        a0[w] += fmaxf(cc0[w] + __uint_as_float(rC_[w] << 16), 0.f);
        a1[w] += fmaxf(cc1[w] + __uint_as_float(rC_[w] & 0xffff0000u), 0.f);
      }
    }
    e += take;
  }
  uint32_t* Srow = reinterpret_cast<uint32_t*>(S + (size_t)gw * ldS + c0);
#pragma unroll
  for (int w = 0; w < 3; ++w)
    if (j2w[w] < nw)
      Srow[j2w[w]] = ((uint32_t)f2bs(a1[w]) << 16) | (uint32_t)f2bs(a0[w]);
}

// ---------------- BN finalize ----------------
__global__ __launch_bounds__(256) void k_bn_finalize(const float* __restrict__ stats,
                                                     const float* __restrict__ gamma,
                                                     const float* __restrict__ beta,
                                                     float* __restrict__ scale,
                                                     float* __restrict__ shift, int N, int O) {
  int c = blockIdx.x * 256 + threadIdx.x;
  if (c >= O) return;
  float mu = stats[c] / (float)N;
  float var = stats[O + c] / (float)N - mu * mu;
  float sc = gamma[c] * rsqrtf(var + 1e-5f);
  scale[c] = sc;
  shift[c] = beta[c] - mu * sc;
}

// ---------------- vertex gather: Vf[v][c] = sum_{(n,g) in CSR(v)} bnrelu(Ef[n][g*O3+c]) ----------------
__global__ __launch_bounds__(256) void k_vgather(
    const int* __restrict__ voff, const int* __restrict__ vidx,
    const float* __restrict__ Ef, const float* __restrict__ scale,
    const float* __restrict__ shift, int use_bn,
    float* __restrict__ Vf, int V, int O, int O3) {
  int idx = blockIdx.x * 256 + threadIdx.x;
  if (idx >= V * O3) return;
  int v = idx / O3;
  int c = idx - v * O3;
  int beg = voff[v], end = voff[v + 1];
  float acc = 0.f;
  for (int e = beg; e < end; ++e) {
    int i = vidx[e];            // face_row*3 + slot
    int n = i / 3;
    int g = i - n * 3;
    int col = g * O3 + c;
    float x = Ef[(size_t)n * O + col];
    if (use_bn) x = fmaxf(fmaf(x, scale[col], shift[col]), 0.f);
    acc += x;
  }
  Vf[idx] = acc;
}

// ---------------- vertex mean gather back ----------------
__global__ __launch_bounds__(256) void k_gather_bf16(const float* __restrict__ Vf,
                                                     const int* __restrict__ faces,
                                                     const float* __restrict__ rv,
                                                     bf16* __restrict__ out,
                                                     int N, int O, int O3) {
  int idx = blockIdx.x * 256 + threadIdx.x;
  if (idx >= N * O) return;
  int n = idx / O;
  int c = idx - n * O;
  int g = c / O3;
  int vert = faces[n * 3 + g];
  out[idx] = f2bf(Vf[(size_t)vert * O3 + (c - g * O3)] * rv[vert]);
}

__global__ __launch_bounds__(256) void k_gather_f32(const float* __restrict__ Vf,
                                                    const int* __restrict__ faces,
                                                    const float* __restrict__ rv,
                                                    float* __restrict__ out,
                                                    int N, int O, int O3) {
  int idx = blockIdx.x * 256 + threadIdx.x;
  if (idx >= N * O) return;
  int n = idx / O;
  int c = idx - n * O;
  int g = c / O3;
  int vert = faces[n * 3 + g];
  out[idx] = Vf[(size_t)vert * O3 + (c - g * O3)] * rv[vert];
}

extern "C" void kernel_launch(void* const* d_in, const int* in_sizes, int n_in,
                              void* d_out, int out_size, void* d_ws, size_t ws_size,
                              hipStream_t stream) {
  (void)n_in; (void)out_size; (void)ws_size;
  const float* x = (const float*)d_in[0];
  const int* ei = (const int*)d_in[1];
  const int* faces = (const int*)d_in[2];
  const int N = in_sizes[0] / 16;
  const int E = in_sizes[1] / 2;
  const int V = 50000;
  const int N_pad = cdiv(N, 128) * 128;   // staging reads go to N_pad-1; stores guarded

  char* p = (char*)d_ws;
  auto carve = [&](size_t bytes) -> char* {
    char* r = p;
    p += (bytes + 255) & ~(size_t)255;
    return r;
  };
  bf16* buf_h = (bf16*)carve((size_t)N_pad * 384 * sizeof(bf16));
  float* buf_e = (float*)carve((size_t)N * 384 * sizeof(float));
  bf16* buf_C = (bf16*)carve((size_t)N * CHUNK * sizeof(bf16));
  bf16* buf_B = (bf16*)carve((size_t)N * CHUNK * sizeof(bf16));
  bf16* buf_S = (bf16*)carve((size_t)N_pad * 1152 * sizeof(bf16));
  float* buf_V = (float*)carve((size_t)V * 192 * sizeof(float));
  bf16* buf_WdT = (bf16*)carve((size_t)1050000 * sizeof(bf16));
  bf16* buf_WbT = (bf16*)carve((size_t)1050000 * sizeof(bf16));
  bf16* buf_W2T = (bf16*)carve((size_t)1500000 * sizeof(bf16));
  int* ideg = (int*)carve((size_t)N * 4);
  int* ivdeg = (int*)carve((size_t)V * 4);
  float* rdegN = (float*)carve((size_t)N * 4);
  float* rdegV = (float*)carve((size_t)V * 4);
  float* stats = (float*)carve(2 * 576 * 4);
  float* scale = (float*)carve(576 * 4);
  float* shift = (float*)carve(576 * 4);
  int* e_off = (int*)carve((size_t)(N + 1) * 4);
  int* e_cur = (int*)carve((size_t)N * 4);
  int* e_src = (int*)carve((size_t)E * 4);
  int* v_off = (int*)carve((size_t)(V + 1) * 4);
  int* v_cur = (int*)carve((size_t)V * 4);
  int* v_idx = (int*)carve((size_t)3 * N * 4);

  hipMemsetAsync(ideg, 0, (size_t)N * 4, stream);
  hipMemsetAsync(ivdeg, 0, (size_t)V * 4, stream);
  k_count<<<cdiv(E, 256), 256, 0, stream>>>(ei + E, ideg, E);
  k_count<<<cdiv(3 * N, 256), 256, 0, stream>>>(faces, ivdeg, 3 * N);
  k_recip<<<cdiv(N, 256), 256, 0, stream>>>(ideg, rdegN, N);
  k_recip<<<cdiv(V, 256), 256, 0, stream>>>(ivdeg, rdegV, V);

  k_scan<<<1, 1024, 0, stream>>>(ideg, e_off, e_cur, N);
  k_scan<<<1, 1024, 0, stream>>>(ivdeg, v_off, v_cur, V);
  k_fill_edges<<<cdiv(E, 256), 256, 0, stream>>>(ei, E, e_cur, e_src);
  k_fill_faces<<<cdiv(3 * N, 256), 256, 0, stream>>>(faces, 3 * N, v_cur, v_idx);

  k_embed<<<cdiv(N * 224, 256), 256, 0, stream>>>(x, buf_h, N);

  const int LF[5] = {196, 96, 192, 384, 384};
  const int LH[5] = {192, 384, 768, 768, 1152};
  const int LO[5] = {96, 192, 384, 384, 576};

  size_t off1 = 0, off2 = 0;
  const int nm = cdiv(N, 128);

  for (int l = 0; l < 5; ++l) {
    const int F = LF[l], H = LH[l], O = LO[l], O3 = O / 3;
    const int F_pad = ((F + 31) / 32) * 32;
    int Hc_last = H % CHUNK;
    if (Hc_last == 0) Hc_last = CHUNK;
    const int H_pad = H - Hc_last + cdiv(Hc_last, 128) * 128;
    const int O_pad = cdiv(O, 128) * 128;
    const float* w1 = (const float*)d_in[4 + l * 4];
    const float* b1 = (const float*)d_in[5 + l * 4];
    const float* w2 = (const float*)d_in[6 + l * 4];
    const float* b2 = (const float*)d_in[7 + l * 4];
    float* Ebuf = (l == 4) ? (float*)d_out : buf_e;
    bf16* WdT = buf_WdT + off1;
    bf16* WbT = buf_WbT + off1;
    bf16* W2T = buf_W2T + off2;
    off1 += (size_t)H_pad * F_pad;
    off2 += (size_t)O_pad * H;

    k_prep_w1<<<cdiv(H_pad * F_pad, 256), 256, 0, stream>>>(w1, WdT, WbT, F, H, F_pad, H_pad);
    k_prep_w2<<<cdiv(O_pad * H, 256), 256, 0, stream>>>(w2, W2T, H, O, O_pad);

    for (int c0 = 0; c0 < H; c0 += CHUNK) {
      int Hc = (H - c0 < CHUNK) ? (H - c0) : CHUNK;
      int nn1 = cdiv(Hc, 128);
      gemm1_mfma<<<nm * nn1, 256, 0, stream>>>(buf_h, F_pad,
                                               WdT + (size_t)c0 * F_pad, WbT + (size_t)c0 * F_pad,
                                               b1, c0, buf_C, buf_B, N, F_pad, Hc, nn1);
      k_edge_gather<<<cdiv(N * 64, 256), 256, 0, stream>>>(e_off, e_src, buf_C, buf_B,
                                                           buf_S, H, c0, N, Hc);
    }

    if (l < 4) hipMemsetAsync(stats, 0, (size_t)2 * O * 4, stream);
    int nn2 = cdiv(O, 128);
    gemm2_mfma<<<nm * nn2, 256, 0, stream>>>(buf_S, H, W2T, H, b2, rdegN, Ebuf,
                                             stats, (l < 4) ? 1 : 0, N, H, O, nn2);

    if (l < 4)
      k_bn_finalize<<<cdiv(O, 256), 256, 0, stream>>>(
          stats, (const float*)d_in[24 + l * 2], (const float*)d_in[25 + l * 2],
          scale, shift, N, O);

    k_vgather<<<cdiv(V * O3, 256), 256, 0, stream>>>(v_off, v_idx, Ebuf, scale, shift,
                                                     (l < 4) ? 1 : 0, buf_V, V, O, O3);
    if (l < 4)
      k_gather_bf16<<<cdiv(N * O, 256), 256, 0, stream>>>(buf_V, faces, rdegV, buf_h, N, O, O3);
    else
      k_gather_f32<<<cdiv(N * O, 256), 256, 0, stream>>>(buf_V, faces, rdegV, (float*)d_out, N, O, O3);
  }
}